// Round 4
// baseline (25.384 us; speedup 1.0000x reference)
//
#include <hip/hip_runtime.h>

// GraphAttentionPooling: B=8, N=6144, F=512, p=3 (N % p == 0, no ragged tail).
// Per group of 3 rows: logits = x @ w + b, att = softmax over the 3 rows,
// out[f] = sum_k att[k] * x[k][f].  Output [B, steps, F, 1] flat = group*F + f.
//
// Memory-bound: 100.7 MB read + 33.6 MB write -> ~21.3 us at the 6.29 TB/s
// copy ceiling. R1/R3: 24.6-24.8 us (5.46 TB/s, 87% of copy ceiling); NT
// stores neutral. This round: 2 groups per wave -- batch 12 KB of loads
// before any store (coarser HBM read/write turnaround, 2x load MLP/wave).
//
// One wave handles groups {2g, 2g+1}: 12 float4 loads up front, butterfly
// reduce 6 logits simultaneously, two 3-way softmaxes, 4 float4 NT stores.

#define GAP_F 512
#define GAP_P 3

typedef float nativef4 __attribute__((ext_vector_type(4)));

__device__ __forceinline__ float dot8(const float4& a, const float4& b,
                                      const float4& c, const float4& d) {
    return a.x * b.x + a.y * b.y + a.z * b.z + a.w * b.w
         + c.x * d.x + c.y * d.y + c.z * d.z + c.w * d.w;
}

__global__ __launch_bounds__(256) void gap_kernel(
    const float* __restrict__ x,   // [ngroups, 3, 512]
    const float* __restrict__ w,   // [512]
    const float* __restrict__ bptr,// [1]
    float* __restrict__ out,       // [ngroups, 512]
    int ngroups)
{
    const int wid  = (int)((blockIdx.x * blockDim.x + threadIdx.x) >> 6);
    const int lane = threadIdx.x & 63;
    const int g0   = wid * 2;            // this wave's first group
    if (g0 >= ngroups) return;
    const bool has2 = (g0 + 1) < ngroups;

    const float* gx = x + (size_t)g0 * (GAP_P * GAP_F);

    // weight fragments (cache-resident after first wave)
    const float4 w0 = *(const float4*)(w + lane * 4);
    const float4 w1 = *(const float4*)(w + 256 + lane * 4);

    // ---- batched loads: 6 rows (2 groups x 3 rows), 12 KB per wave ----
    const float4 xA00 = *(const float4*)(gx + 0 * GAP_F + lane * 4);
    const float4 xA01 = *(const float4*)(gx + 0 * GAP_F + 256 + lane * 4);
    const float4 xA10 = *(const float4*)(gx + 1 * GAP_F + lane * 4);
    const float4 xA11 = *(const float4*)(gx + 1 * GAP_F + 256 + lane * 4);
    const float4 xA20 = *(const float4*)(gx + 2 * GAP_F + lane * 4);
    const float4 xA21 = *(const float4*)(gx + 2 * GAP_F + 256 + lane * 4);

    const float* gx2 = gx + (has2 ? (GAP_P * GAP_F) : 0);  // clamp: re-read g0 if no g1
    const float4 xB00 = *(const float4*)(gx2 + 0 * GAP_F + lane * 4);
    const float4 xB01 = *(const float4*)(gx2 + 0 * GAP_F + 256 + lane * 4);
    const float4 xB10 = *(const float4*)(gx2 + 1 * GAP_F + lane * 4);
    const float4 xB11 = *(const float4*)(gx2 + 1 * GAP_F + 256 + lane * 4);
    const float4 xB20 = *(const float4*)(gx2 + 2 * GAP_F + lane * 4);
    const float4 xB21 = *(const float4*)(gx2 + 2 * GAP_F + 256 + lane * 4);

    // ---- per-lane dot partials, 6 logits ----
    float dA0 = dot8(xA00, w0, xA01, w1);
    float dA1 = dot8(xA10, w0, xA11, w1);
    float dA2 = dot8(xA20, w0, xA21, w1);
    float dB0 = dot8(xB00, w0, xB01, w1);
    float dB1 = dot8(xB10, w0, xB11, w1);
    float dB2 = dot8(xB20, w0, xB21, w1);

    // butterfly reduce across the 64-lane wave (every lane ends with full sum)
    #pragma unroll
    for (int off = 32; off >= 1; off >>= 1) {
        dA0 += __shfl_xor(dA0, off, 64);
        dA1 += __shfl_xor(dA1, off, 64);
        dA2 += __shfl_xor(dA2, off, 64);
        dB0 += __shfl_xor(dB0, off, 64);
        dB1 += __shfl_xor(dB1, off, 64);
        dB2 += __shfl_xor(dB2, off, 64);
    }

    const float b = *bptr;   // shift-invariant under softmax, kept for fidelity

    // softmax group A
    float mA = fmaxf(fmaxf(dA0, dA1), dA2);
    float eA0 = expf(dA0 - mA + b - b), eA1 = expf(dA1 - mA), eA2 = expf(dA2 - mA);
    float ivA = 1.0f / (eA0 + eA1 + eA2);
    const float a0 = eA0 * ivA, a1 = eA1 * ivA, a2 = eA2 * ivA;
    // softmax group B
    float mB = fmaxf(fmaxf(dB0, dB1), dB2);
    float eB0 = expf(dB0 - mB), eB1 = expf(dB1 - mB), eB2 = expf(dB2 - mB);
    float ivB = 1.0f / (eB0 + eB1 + eB2);
    const float b0 = eB0 * ivB, b1 = eB1 * ivB, b2 = eB2 * ivB;

    nativef4 oA0, oA1, oB0, oB1;
    oA0.x = a0 * xA00.x + a1 * xA10.x + a2 * xA20.x;
    oA0.y = a0 * xA00.y + a1 * xA10.y + a2 * xA20.y;
    oA0.z = a0 * xA00.z + a1 * xA10.z + a2 * xA20.z;
    oA0.w = a0 * xA00.w + a1 * xA10.w + a2 * xA20.w;
    oA1.x = a0 * xA01.x + a1 * xA11.x + a2 * xA21.x;
    oA1.y = a0 * xA01.y + a1 * xA11.y + a2 * xA21.y;
    oA1.z = a0 * xA01.z + a1 * xA11.z + a2 * xA21.z;
    oA1.w = a0 * xA01.w + a1 * xA11.w + a2 * xA21.w;
    oB0.x = b0 * xB00.x + b1 * xB10.x + b2 * xB20.x;
    oB0.y = b0 * xB00.y + b1 * xB10.y + b2 * xB20.y;
    oB0.z = b0 * xB00.z + b1 * xB10.z + b2 * xB20.z;
    oB0.w = b0 * xB00.w + b1 * xB10.w + b2 * xB20.w;
    oB1.x = b0 * xB01.x + b1 * xB11.x + b2 * xB21.x;
    oB1.y = b0 * xB01.y + b1 * xB11.y + b2 * xB21.y;
    oB1.z = b0 * xB01.z + b1 * xB11.z + b2 * xB21.z;
    oB1.w = b0 * xB01.w + b1 * xB11.w + b2 * xB21.w;

    // ---- batched stores: 4 KB per wave, nontemporal ----
    float* go = out + (size_t)g0 * GAP_F;
    __builtin_nontemporal_store(oA0, (nativef4*)(go + lane * 4));
    __builtin_nontemporal_store(oA1, (nativef4*)(go + 256 + lane * 4));
    if (has2) {
        float* go2 = go + GAP_F;
        __builtin_nontemporal_store(oB0, (nativef4*)(go2 + lane * 4));
        __builtin_nontemporal_store(oB1, (nativef4*)(go2 + 256 + lane * 4));
    }
}

extern "C" void kernel_launch(void* const* d_in, const int* in_sizes, int n_in,
                              void* d_out, int out_size, void* d_ws, size_t ws_size,
                              hipStream_t stream) {
    const float* x = (const float*)d_in[0];   // [B, N, F] fp32
    const float* w = (const float*)d_in[1];   // [F, 1]
    const float* b = (const float*)d_in[2];   // [1]
    float* out = (float*)d_out;               // [B, steps, F, 1]

    const int ngroups = in_sizes[0] / (GAP_P * GAP_F);  // B * steps = 16384
    const int nwaves  = (ngroups + 1) / 2;               // 2 groups per wave
    const int waves_per_block = 4;                       // 256 threads
    const int nblocks = (nwaves + waves_per_block - 1) / waves_per_block;
    gap_kernel<<<nblocks, 256, 0, stream>>>(x, w, b, out, ngroups);
}

// Round 5
// 24.635 us; speedup vs baseline: 1.0304x; 1.0304x over previous
//
#include <hip/hip_runtime.h>

// GraphAttentionPooling: B=8, N=6144, F=512, p=3 (N % p == 0, no ragged tail).
// Per group of 3 rows: logits = x @ w + b, att = softmax over the 3 rows,
// out[f] = sum_k att[k] * x[k][f].  Output [B, steps, F, 1] flat = group*F + f.
//
// FINAL (reverted to R3 best, 24.57 us): memory-bound roofline.
//   traffic = 100.7 MB read + 33.6 MB write = 134.2 MB compulsory
//   24.57 us -> 5.46 TB/s = 87% of the 6.29 TB/s D2D copy ceiling
//   (reference band for streaming kernels on this chip: LN 82%, RMSNorm 86%).
// Refuted levers: NT-store L2 pollution (R3: neutral), read/write turnaround
// batching via 2 groups/wave (R4: -3%). VALU work is ~7% of memory cycles ->
// not latency/VALU-bound. No traffic reduction possible (fp32 out, each input
// byte needed exactly once).
//
// One wave (64 lanes) per group; each lane owns floats {lane*4..+3} and
// {256+lane*4..+3} of each 512-float row (two float4 loads per row, fully
// coalesced: 64 lanes x 16 B = 1 KiB per instruction).

#define GAP_F 512
#define GAP_P 3

typedef float nativef4 __attribute__((ext_vector_type(4)));

__global__ __launch_bounds__(256) void gap_kernel(
    const float* __restrict__ x,   // [ngroups, 3, 512]
    const float* __restrict__ w,   // [512]
    const float* __restrict__ bptr,// [1]
    float* __restrict__ out,       // [ngroups, 512]
    int ngroups)
{
    const int gwave = (int)((blockIdx.x * blockDim.x + threadIdx.x) >> 6);
    const int lane  = threadIdx.x & 63;
    if (gwave >= ngroups) return;

    const float* gx = x + (size_t)gwave * (GAP_P * GAP_F);

    // weight fragments (L1/L2 resident after first wave)
    const float4 w0 = *(const float4*)(w + lane * 4);
    const float4 w1 = *(const float4*)(w + 256 + lane * 4);

    // three rows, two float4 each
    const float4 x00 = *(const float4*)(gx + 0 * GAP_F + lane * 4);
    const float4 x01 = *(const float4*)(gx + 0 * GAP_F + 256 + lane * 4);
    const float4 x10 = *(const float4*)(gx + 1 * GAP_F + lane * 4);
    const float4 x11 = *(const float4*)(gx + 1 * GAP_F + 256 + lane * 4);
    const float4 x20 = *(const float4*)(gx + 2 * GAP_F + lane * 4);
    const float4 x21 = *(const float4*)(gx + 2 * GAP_F + 256 + lane * 4);

    // per-lane dot partials
    float d0 = x00.x * w0.x + x00.y * w0.y + x00.z * w0.z + x00.w * w0.w
             + x01.x * w1.x + x01.y * w1.y + x01.z * w1.z + x01.w * w1.w;
    float d1 = x10.x * w0.x + x10.y * w0.y + x10.z * w0.z + x10.w * w0.w
             + x11.x * w1.x + x11.y * w1.y + x11.z * w1.z + x11.w * w1.w;
    float d2 = x20.x * w0.x + x20.y * w0.y + x20.z * w0.z + x20.w * w0.w
             + x21.x * w1.x + x21.y * w1.y + x21.z * w1.z + x21.w * w1.w;

    // butterfly reduce across the 64-lane wave (every lane ends with full sum)
    #pragma unroll
    for (int off = 32; off >= 1; off >>= 1) {
        d0 += __shfl_xor(d0, off, 64);
        d1 += __shfl_xor(d1, off, 64);
        d2 += __shfl_xor(d2, off, 64);
    }

    const float b = *bptr;   // shift-invariant under softmax, kept for fidelity
    const float l0 = d0 + b, l1 = d1 + b, l2 = d2 + b;
    const float m  = fmaxf(fmaxf(l0, l1), l2);
    const float e0 = expf(l0 - m), e1 = expf(l1 - m), e2 = expf(l2 - m);
    const float inv = 1.0f / (e0 + e1 + e2);
    const float a0 = e0 * inv, a1 = e1 * inv, a2 = e2 * inv;

    nativef4 o0, o1;
    o0.x = a0 * x00.x + a1 * x10.x + a2 * x20.x;
    o0.y = a0 * x00.y + a1 * x10.y + a2 * x20.y;
    o0.z = a0 * x00.z + a1 * x10.z + a2 * x20.z;
    o0.w = a0 * x00.w + a1 * x10.w + a2 * x20.w;
    o1.x = a0 * x01.x + a1 * x11.x + a2 * x21.x;
    o1.y = a0 * x01.y + a1 * x11.y + a2 * x21.y;
    o1.z = a0 * x01.z + a1 * x11.z + a2 * x21.z;
    o1.w = a0 * x01.w + a1 * x11.w + a2 * x21.w;

    float* go = out + (size_t)gwave * GAP_F;
    // nontemporal: output is write-once, never re-read by this kernel.
    __builtin_nontemporal_store(o0, (nativef4*)(go + lane * 4));
    __builtin_nontemporal_store(o1, (nativef4*)(go + 256 + lane * 4));
}

extern "C" void kernel_launch(void* const* d_in, const int* in_sizes, int n_in,
                              void* d_out, int out_size, void* d_ws, size_t ws_size,
                              hipStream_t stream) {
    const float* x = (const float*)d_in[0];   // [B, N, F] fp32
    const float* w = (const float*)d_in[1];   // [F, 1]
    const float* b = (const float*)d_in[2];   // [1]
    float* out = (float*)d_out;               // [B, steps, F, 1]

    const int ngroups = in_sizes[0] / (GAP_P * GAP_F);  // B * steps = 16384

    const int waves_per_block = 4;                       // 256 threads
    const int nblocks = (ngroups + waves_per_block - 1) / waves_per_block;
    gap_kernel<<<nblocks, 256, 0, stream>>>(x, w, b, out, ngroups);
}